// Round 8
// baseline (216.578 us; speedup 1.0000x reference)
//
#include <hip/hip_runtime.h>
#include <hip/hip_bf16.h>

// CARAFE fp32 pipeline. x(4,256,64,64), Wc(64,256), bc(64), We(100,64,3,3),
// be(100) -> out(4,256,128,128). SF=2 K=5 G=1 CC=64 EK=3. All I/O fp32.
//
// ws layout (fp32 elements):
//   comp  [4][64][66*66]   zero-padded halo   @ 0          (1,115,136)
//   Wr2   [ij4][kt5][cc64][48]  q*5+kk packed @ 1,115,136  (61,440 of 64,512)
//   logit [16384 px][100]  e = 4k+ij          @ 1,179,648  (1,638,400)
// total 11,272,192 B. Host-gated on ws_size; fallback = fused kernel.
//
// Round 11 (this round): REVERT k2 to the round-5 v3 (48.8us known-good;
// v4/v5 rewrites both lost -- 0-for-3 on LDS relayouts, stop). New lever:
// k1 v2. Accounting showed k1 ~40us hidden under the top-5 cutoff: it read
// x 8x (once per 8-wide cc group) = 134MB. v2: 16 cc per thread (acc[16]),
// 4 groups -> 67MB x + 18MB write ~= 85MB; unroll 8 keeps 8 wave-loads in
// flight (4 waves/CU x 2KB = 8KB/CU in flight > ~5KB needed for ~5TB/s).
// k2s stays v2 (coalesced LDS-staged softmax, neutral-to-positive r6->r7).

#define COMP_F 0
#define WR_F   1115136
#define LOG_F  1179648
#define WS_NEED 11272192ull
#define CSTR 4356  // 66*66 comp per-channel stride

// ---------------- K0: We(100,576) -> Wr2[ij][kt][cc][48] ----------------
// Wr2 row (48 floats, 192B-aligned) holds w[q*5+kk] for one (ij,kt,cc).
__global__ void k0_wr(const float* __restrict__ We, float* __restrict__ ws) {
    int tid = blockIdx.x * blockDim.x + threadIdx.x;
    if (tid >= 4 * 5 * 64 * 45) return;
    int kk = tid % 5;
    int q  = (tid / 5) % 9;
    int cc = (tid / 45) % 64;
    int kt = (tid / 2880) % 5;
    int ij = tid / 14400;
    ws[WR_F + (size_t)(((ij * 5 + kt) * 64 + cc)) * 48 + q * 5 + kk] =
        We[(size_t)(4 * (kt * 5 + kk) + ij) * 576 + cc * 9 + q];
}

// ---------------- K1 v2: 1x1 compressor 256->64, padded comp out --------
// grid 1024 x 64thr: b = ccg*256 + pw; ccg 0..3 -> 16 cc per thread.
// x read 4x (67MB) instead of 8x (134MB). unroll 8: 8 independent 256B
// wave-loads in flight. Weights via wave-uniform address -> s_load/SGPR.
__global__ __launch_bounds__(64) void k1_comp(const float* __restrict__ x,
                                              const float* __restrict__ Wc,
                                              const float* __restrict__ bc,
                                              float* __restrict__ ws) {
    int b   = blockIdx.x;
    int pw  = b & 255;
    int ccg = b >> 8;          // 0..3, wave-uniform
    int n = pw >> 6, h = pw & 63, w = threadIdx.x;
    int cc0 = ccg * 16;

    float acc[16];
#pragma unroll
    for (int u = 0; u < 16; ++u) acc[u] = 0.f;

    const float* xp = x + (size_t)n * 256 * 4096 + h * 64 + w;
#pragma unroll 8
    for (int c = 0; c < 256; ++c) {
        float xv = xp[(size_t)c * 4096];
#pragma unroll
        for (int u = 0; u < 16; ++u)
            acc[u] += xv * Wc[(cc0 + u) * 256 + c];  // uniform -> s_load
    }

    float* compb = ws + COMP_F + (size_t)(n * 64 + cc0) * CSTR;
#pragma unroll
    for (int u = 0; u < 16; ++u) {
        float* cb_ = compb + (size_t)u * CSTR;
        cb_[(h + 1) * 66 + (w + 1)] = acc[u] + bc[cc0 + u];
        // zero halo border (pad=1 of the 3x3 conv)
        if (w < 2) cb_[(h + 1) * 66 + (w ? 65 : 0)] = 0.f;
        if (h == 0)  { cb_[w] = 0.f;           if (w < 2) cb_[64 + w] = 0.f; }
        if (h == 63) { cb_[65 * 66 + w] = 0.f; if (w < 2) cb_[65 * 66 + 64 + w] = 0.f; }
    }
}

// ---------------- K2 v3: 3x3 encoder -> raw logits ----------------------
// (Round-5 known-good, 48.8us. v4/v5 relayouts both regressed; reverted.)
// grid 1280 = kt*256 + tile; block 256 thr = 4 ij-waves. kt gives k-range
// [kt*5, kt*5+5). comp 8x8 tile + 3x3 halo in LDS, row stride 12 (2-way
// bank aliasing = free). Weights read with wave-uniform addresses from
// global Wr2 -> s_load/SGPR (SMEM pipe), NOT the DS pipe. Per channel:
// 9 ds_read + 45 v_fmac (SGPR weight operand).
__global__ __launch_bounds__(256, 5) void k2_enc(const float* __restrict__ be,
                                                 float* __restrict__ ws) {
    __shared__ __align__(16) float compT[64 * 120];  // 30720 B
    int b    = blockIdx.x;
    int tile = b & 255;                              // low bits: same-tile
    int kt   = b >> 8;                               // 0..4, siblings same XCD
    int n = tile >> 6, th = (tile >> 3) & 7, tw = tile & 7;
    int h0 = th * 8, w0 = tw * 8;
    int tid = threadIdx.x;

    const float* compn = ws + COMP_F + (size_t)n * 64 * CSTR;
    // stage comp halo tile: compT[c*120 + r*12 + q] = comp[c][h0+r][w0+q]
    for (int e = tid; e < 6400; e += 256) {
        int c = e / 100, rq = e % 100, r = rq / 10, q = rq % 10;
        compT[c * 120 + r * 12 + q] =
            compn[(size_t)c * CSTR + (h0 + r) * 66 + (w0 + q)];
    }
    __syncthreads();

    int lane = tid & 63;
    int ij   = __builtin_amdgcn_readfirstlane(tid >> 6);  // force scalar
    int py = lane >> 3, pxx = lane & 7;

    const float* wb = ws + WR_F + (size_t)((ij * 5 + kt) * 64) * 48;

    float acc[5];
#pragma unroll
    for (int kk = 0; kk < 5; ++kk) acc[kk] = be[4 * (kt * 5 + kk) + ij];

#pragma unroll 2
    for (int c = 0; c < 64; ++c) {
        const float* cp = compT + c * 120 + py * 12 + pxx;
        float cv[9];
#pragma unroll
        for (int dy = 0; dy < 3; ++dy)
#pragma unroll
            for (int dx = 0; dx < 3; ++dx)
                cv[dy * 3 + dx] = cp[dy * 12 + dx];
        const float* w = wb + c * 48;                // uniform -> s_load
#pragma unroll
        for (int q = 0; q < 9; ++q) {
            float v = cv[q];
#pragma unroll
            for (int kk = 0; kk < 5; ++kk)
                acc[kk] += v * w[q * 5 + kk];        // v_fmac v, s, v
        }
    }

    float* lp = ws + LOG_F +
                (size_t)(n * 4096 + (h0 + py) * 64 + (w0 + pxx)) * 100 + ij;
#pragma unroll
    for (int kk = 0; kk < 5; ++kk) lp[4 * (kt * 5 + kk)] = acc[kk];
}

// ---------------- K2s v2: in-place softmax, LDS-coalesced ---------------
// grid 256 x 256thr: block handles 64 px. Global I/O as coalesced float4
// through LDS. Softmax thread-task = (pxl, ij); LDS reads at pxl*100+4k+ij
// are 2-way bank aliased max (100 mod 32 = 4) = free.
__global__ __launch_bounds__(256) void k2s_sm(float* __restrict__ ws) {
    __shared__ __align__(16) float L[64 * 100];  // 25600 B
    float* gp = ws + LOG_F + (size_t)blockIdx.x * 6400;
    int tid = threadIdx.x;

    for (int e4 = tid; e4 < 1600; e4 += 256)
        ((float4*)L)[e4] = ((const float4*)gp)[e4];
    __syncthreads();

    int pxl = tid >> 2, ij = tid & 3;
    float* p = L + pxl * 100 + ij;
    float m[25];
#pragma unroll
    for (int k = 0; k < 25; ++k) m[k] = p[4 * k];
    float mx = m[0];
#pragma unroll
    for (int k = 1; k < 25; ++k) mx = fmaxf(mx, m[k]);
    float ss = 0.f;
#pragma unroll
    for (int k = 0; k < 25; ++k) { m[k] = __expf(m[k] - mx); ss += m[k]; }
    float inv = 1.f / ss;
#pragma unroll
    for (int k = 0; k < 25; ++k) p[4 * k] = m[k] * inv;
    __syncthreads();

    for (int e4 = tid; e4 < 1600; e4 += 256)
        ((float4*)gp)[e4] = ((const float4*)L)[e4];
}

// ---------------- K3 v3: reassembly (masks pre-normalized) --------------
// grid 1024 x 256thr: b = cchunk*64 + tile. 16x16 px tile, 16-c chunk.
// x tile in LDS as [cg8][r20][q20][2] (channel pairs innermost, row stride
// 42 words): one ds_read_b64 per tap serves 2 channels, lanes contiguous
// 8B (conflict-free), tap offsets fold to immediates.
// Taps OUTER, channels inner: mask float4 is a per-tap transient; resident
// state is float2 A[8][4] = 64 VGPRs, statically indexed (no scratch).
// Plain launch_bounds(256) -- no min-waves hint (the hint caps VGPR at
// ~512/(2*arg) on this toolchain and forced spill in rounds 6/7).
__global__ __launch_bounds__(256) void k3_out(const float* __restrict__ x,
                                              const float* __restrict__ ws,
                                              float* __restrict__ out) {
    __shared__ __align__(16) float xt[8 * 20 * 42];  // 26880 B
    int b      = blockIdx.x;
    int tile   = b & 63;
    int cchunk = b >> 6;
    int n = tile >> 4, ty0 = ((tile >> 2) & 3) * 16, tx0 = (tile & 3) * 16;
    int c0 = cchunk * 16;

    int py = threadIdx.x >> 4, pxx = threadIdx.x & 15;
    int h = ty0 + py, w = tx0 + pxx;

    // stage x halo tile as float2 (halo col origin tx0-2 is even -> the
    // 20-wide row is 10 aligned float2s, all-or-nothing in bounds).
    const float* xn = x + (size_t)(n * 256 + c0) * 4096;
    for (int e2 = threadIdx.x; e2 < 3200; e2 += 256) {
        int c = e2 / 200, rem = e2 % 200, r = rem / 10, q2 = rem % 10;
        int hh = ty0 + r - 2, ww = tx0 + 2 * q2 - 2;
        float2 v = {0.f, 0.f};
        if (hh >= 0 && hh < 64 && ww >= 0 && ww < 64)
            v = *(const float2*)(xn + (size_t)c * 4096 + hh * 64 + ww);
        int a0 = (c >> 1) * 840 + r * 42 + 4 * q2 + (c & 1);
        xt[a0]     = v.x;
        xt[a0 + 2] = v.y;
    }
    __syncthreads();

    const float* lp = ws + LOG_F + (size_t)(n * 4096 + h * 64 + w) * 100;
    const float* vb = xt + py * 42 + pxx * 2;

    float2 A[8][4];
#pragma unroll
    for (int cg = 0; cg < 8; ++cg)
#pragma unroll
        for (int u = 0; u < 4; ++u) A[cg][u] = {0.f, 0.f};

    for (int dy = 0; dy < 5; ++dy) {
        const float4* mkp = (const float4*)lp + dy * 5;  // 5 taps this row
        const float* vrow = vb + dy * 42;
#pragma unroll
        for (int dx = 0; dx < 5; ++dx) {
            float4 mk = mkp[dx];                         // transient, L2-hot
#pragma unroll
            for (int cg = 0; cg < 8; ++cg) {
                float2 v = *(const float2*)(vrow + cg * 840 + dx * 2);
                A[cg][0].x += v.x * mk.x; A[cg][0].y += v.y * mk.x;
                A[cg][1].x += v.x * mk.y; A[cg][1].y += v.y * mk.y;
                A[cg][2].x += v.x * mk.z; A[cg][2].y += v.y * mk.z;
                A[cg][3].x += v.x * mk.w; A[cg][3].y += v.y * mk.w;
            }
        }
    }

#pragma unroll
    for (int cg = 0; cg < 8; ++cg) {
        int c = cg * 2;
        size_t ob0 = (((size_t)(n * 256 + c0 + c) * 128) + 2 * h) * 128 + 2 * w;
        float2 r0 = {A[cg][0].x, A[cg][1].x}, r1 = {A[cg][2].x, A[cg][3].x};
        *(float2*)(out + ob0)       = r0;
        *(float2*)(out + ob0 + 128) = r1;
        size_t ob1 = ob0 + 16384;
        float2 r2 = {A[cg][0].y, A[cg][1].y}, r3 = {A[cg][2].y, A[cg][3].y};
        *(float2*)(out + ob1)       = r2;
        *(float2*)(out + ob1 + 128) = r3;
    }
}

// ---------------- Fallback: fused kernel, fp32-only ---------------------
__global__ __launch_bounds__(256) void k_fused(const float* __restrict__ x,
                                               const float* __restrict__ Wc,
                                               const float* __restrict__ bc,
                                               const float* __restrict__ We,
                                               const float* __restrict__ be,
                                               float* __restrict__ out) {
    __shared__ float compS[64 * 101];
    int n = blockIdx.x >> 6, tile = blockIdx.x & 63;
    int ty0 = (tile >> 3) * 8, tx0 = (tile & 7) * 8;
    const float* xn = x + (size_t)n * 256 * 4096;
    {
        int pa = threadIdx.x & 127;
        int ga = __builtin_amdgcn_readfirstlane(threadIdx.x >> 7);
        bool act = pa < 100;
        int ah = ty0 + pa / 10 - 1, aw = tx0 + pa % 10 - 1;
        bool inb = act && ah >= 0 && ah < 64 && aw >= 0 && aw < 64;
        int xoff = ah * 64 + aw;
        float acc[32];
#pragma unroll
        for (int i = 0; i < 32; ++i) acc[i] = 0.f;
        for (int c = 0; c < 256; ++c) {
            float xv = inb ? xn[(size_t)c * 4096 + xoff] : 0.f;
#pragma unroll
            for (int i = 0; i < 32; ++i) acc[i] += xv * Wc[(ga * 32 + i) * 256 + c];
        }
        if (act)
#pragma unroll
            for (int i = 0; i < 32; ++i) {
                int cc = ga * 32 + i;
                compS[cc * 101 + pa] = inb ? acc[i] + bc[cc] : 0.f;
            }
    }
    __syncthreads();
    int px = threadIdx.x & 63;
    int ij = __builtin_amdgcn_readfirstlane(threadIdx.x >> 6);
    int py = px >> 3, pxx = px & 7;
    int h = ty0 + py, w = tx0 + pxx;
    float m[25];
#pragma unroll
    for (int k = 0; k < 25; ++k) m[k] = be[4 * k + ij];
    for (int cc = 0; cc < 64; ++cc) {
        float cv[9];
#pragma unroll
        for (int dy = 0; dy < 3; ++dy)
#pragma unroll
            for (int dx = 0; dx < 3; ++dx)
                cv[dy * 3 + dx] = compS[cc * 101 + (py + dy) * 10 + (pxx + dx)];
        int base = cc * 9;
#pragma unroll
        for (int k = 0; k < 25; ++k) {
            int eb = (4 * k + ij) * 576 + base;
            float s = 0.f;
#pragma unroll
            for (int qb = 0; qb < 9; ++qb) s += cv[qb] * We[eb + qb];
            m[k] += s;
        }
    }
    float mxv = m[0];
#pragma unroll
    for (int k = 1; k < 25; ++k) mxv = fmaxf(mxv, m[k]);
    float ss = 0.f;
#pragma unroll
    for (int k = 0; k < 25; ++k) { m[k] = __expf(m[k] - mxv); ss += m[k]; }
    float inv = 1.f / ss;
#pragma unroll
    for (int k = 0; k < 25; ++k) m[k] *= inv;
    int offs[25];
    unsigned vm = 0;
#pragma unroll
    for (int t = 0; t < 25; ++t) {
        int hh = h + t / 5 - 2, ww = w + t % 5 - 2;
        bool v = hh >= 0 && hh < 64 && ww >= 0 && ww < 64;
        offs[t] = v ? hh * 64 + ww : 0;
        if (v) vm |= 1u << t;
    }
    size_t outp = ((size_t)n * 256 * 128 + (2 * h + (ij >> 1))) * 128 + (2 * w + (ij & 1));
    for (int c = 0; c < 256; ++c) {
        const float* xc = xn + (size_t)c * 4096;
        float sum = 0.f;
#pragma unroll
        for (int t = 0; t < 25; ++t) {
            float v = ((vm >> t) & 1u) ? xc[offs[t]] : 0.f;
            sum += v * m[t];
        }
        out[outp + (size_t)c * 16384] = sum;
    }
}

extern "C" void kernel_launch(void* const* d_in, const int* in_sizes, int n_in,
                              void* d_out, int out_size, void* d_ws, size_t ws_size,
                              hipStream_t stream) {
    const float* x  = (const float*)d_in[0];
    const float* Wc = (const float*)d_in[1];
    const float* bc = (const float*)d_in[2];
    const float* We = (const float*)d_in[3];
    const float* be = (const float*)d_in[4];
    float* out = (float*)d_out;

    if (ws_size >= WS_NEED && d_ws != nullptr) {
        float* ws = (float*)d_ws;
        hipLaunchKernelGGL(k0_wr,   dim3(226),  dim3(256), 0, stream, We, ws);
        hipLaunchKernelGGL(k1_comp, dim3(1024), dim3(64),  0, stream, x, Wc, bc, ws);
        hipLaunchKernelGGL(k2_enc,  dim3(1280), dim3(256), 0, stream, be, ws);
        hipLaunchKernelGGL(k2s_sm,  dim3(256),  dim3(256), 0, stream, ws);
        hipLaunchKernelGGL(k3_out,  dim3(1024), dim3(256), 0, stream, x, ws, out);
    } else {
        hipLaunchKernelGGL(k_fused, dim3(256),  dim3(256), 0, stream,
                           x, Wc, bc, We, be, out);
    }
}

// Round 9
// 183.861 us; speedup vs baseline: 1.1779x; 1.1779x over previous
//
#include <hip/hip_runtime.h>
#include <hip/hip_bf16.h>

// CARAFE fp32 pipeline. x(4,256,64,64), Wc(64,256), bc(64), We(100,64,3,3),
// be(100) -> out(4,256,128,128). SF=2 K=5 G=1 CC=64 EK=3. All I/O fp32.
//
// ws layout (fp32 elements):
//   comp  [4][64][66*66]   zero-padded halo   @ 0          (1,115,136)
//   Wr2   [ij4][kt5][cc64][48]  q*5+kk packed @ 1,115,136  (61,440 of 64,512)
//   logit [16384 px][100]  e = 4k+ij          @ 1,179,648  (1,638,400)
//     NB: first 16,384 floats of logit double as WcT[c256][cc64] during
//     k0->k1 (dead space until k2 writes logits; stream-serialized).
// total 11,272,192 B. Host-gated on ws_size; fallback = fused kernel.
//
// Round 12 (this round): k1 v3. Round-11 post-mortem: k1 v2 = 70us,
// VALUBusy 10%, 1 wave/SIMD; per-c weight path = 16 SCATTERED s_load_dword
// (stride-256) with nothing to hide the latency -> pure stall. v3:
// (1) k0 also writes WcT (transposed Wc) into the dead logit region ->
//     per-c weights are 32B contiguous = one s_load_dwordx8;
// (2) block 256thr, thread=px, 8 cc/thread, grid 512 = 8ccq x 64pxtile ->
//     2 waves/SIMD, coalesced 1KB x-loads; b=ccq*64+pxtile keeps all 8
//     cc-siblings of a pxtile on one XCD (64 = 0 mod 8) -> x 2MB/XCD in L2.
// k2 v3 / k2s v2 / k3 v3 unchanged (known-good).

#define COMP_F 0
#define WR_F   1115136
#define LOG_F  1179648
#define WS_NEED 11272192ull
#define CSTR 4356  // 66*66 comp per-channel stride

// ---------------- K0: Wr2 repack + WcT transpose ------------------------
// job1 (tid < 57600): We(100,576) -> Wr2[ij][kt][cc][48], row = q*5+kk.
// job2 (tid >= 57600): Wc(64,256) -> WcT[c][cc] @ LOG_F (16,384 floats).
__global__ void k0_wr(const float* __restrict__ We, const float* __restrict__ Wc,
                      float* __restrict__ ws) {
    int tid = blockIdx.x * blockDim.x + threadIdx.x;
    if (tid < 57600) {
        int kk = tid % 5;
        int q  = (tid / 5) % 9;
        int cc = (tid / 45) % 64;
        int kt = (tid / 2880) % 5;
        int ij = tid / 14400;
        ws[WR_F + (size_t)(((ij * 5 + kt) * 64 + cc)) * 48 + q * 5 + kk] =
            We[(size_t)(4 * (kt * 5 + kk) + ij) * 576 + cc * 9 + q];
    } else if (tid < 57600 + 16384) {
        int t2 = tid - 57600;
        int c = t2 >> 6, cc = t2 & 63;
        ws[LOG_F + t2] = Wc[cc * 256 + c];
    }
}

// ---------------- K1 v3: 1x1 compressor 256->64, padded comp out --------
// grid 512 = ccq*64 + pxtile; block 256thr; thread = one pixel, 8 cc.
// Weights from WcT (contiguous 32B/c -> s_load_dwordx8). x loads coalesced
// (256 consecutive px per block). 2 blocks/CU = 2 waves/SIMD.
__global__ __launch_bounds__(256) void k1_comp(const float* __restrict__ x,
                                               const float* __restrict__ bc,
                                               float* __restrict__ ws) {
    int b      = blockIdx.x;
    int pxtile = b & 63;       // 0..63 ; b%8 = pxtile%8 -> cc-siblings same XCD
    int ccq    = b >> 6;       // 0..7, wave-uniform
    int tid = threadIdx.x;
    int n   = pxtile >> 4;
    int off = (pxtile & 15) * 256 + tid;   // 0..4095 within image
    int h = off >> 6, w = off & 63;
    int cc0 = ccq * 8;

    const float* wT = ws + LOG_F;          // WcT[c][64]
    const float* xp = x + (size_t)n * 256 * 4096 + off;

    float acc[8];
#pragma unroll
    for (int u = 0; u < 8; ++u) acc[u] = 0.f;

#pragma unroll 8
    for (int c = 0; c < 256; ++c) {
        float xv = xp[(size_t)c * 4096];
        const float* wr = wT + c * 64 + cc0;   // uniform -> s_load_dwordx8
#pragma unroll
        for (int u = 0; u < 8; ++u) acc[u] += xv * wr[u];
    }

    float* compb = ws + COMP_F + (size_t)(n * 64 + cc0) * CSTR;
#pragma unroll
    for (int u = 0; u < 8; ++u) {
        float* cb_ = compb + (size_t)u * CSTR;
        cb_[(h + 1) * 66 + (w + 1)] = acc[u] + bc[cc0 + u];
        // zero halo border (pad=1 of the 3x3 conv)
        if (w < 2) cb_[(h + 1) * 66 + (w ? 65 : 0)] = 0.f;
        if (h == 0)  { cb_[w] = 0.f;           if (w < 2) cb_[64 + w] = 0.f; }
        if (h == 63) { cb_[65 * 66 + w] = 0.f; if (w < 2) cb_[65 * 66 + 64 + w] = 0.f; }
    }
}

// ---------------- K2 v3: 3x3 encoder -> raw logits ----------------------
// (Round-5 known-good, 48.8us.)
// grid 1280 = kt*256 + tile; block 256 thr = 4 ij-waves. kt gives k-range
// [kt*5, kt*5+5). comp 8x8 tile + 3x3 halo in LDS, row stride 12 (2-way
// bank aliasing = free). Weights read with wave-uniform addresses from
// global Wr2 -> s_load/SGPR (SMEM pipe), NOT the DS pipe. Per channel:
// 9 ds_read + 45 v_fmac (SGPR weight operand).
__global__ __launch_bounds__(256, 5) void k2_enc(const float* __restrict__ be,
                                                 float* __restrict__ ws) {
    __shared__ __align__(16) float compT[64 * 120];  // 30720 B
    int b    = blockIdx.x;
    int tile = b & 255;                              // low bits: same-tile
    int kt   = b >> 8;                               // 0..4, siblings same XCD
    int n = tile >> 6, th = (tile >> 3) & 7, tw = tile & 7;
    int h0 = th * 8, w0 = tw * 8;
    int tid = threadIdx.x;

    const float* compn = ws + COMP_F + (size_t)n * 64 * CSTR;
    // stage comp halo tile: compT[c*120 + r*12 + q] = comp[c][h0+r][w0+q]
    for (int e = tid; e < 6400; e += 256) {
        int c = e / 100, rq = e % 100, r = rq / 10, q = rq % 10;
        compT[c * 120 + r * 12 + q] =
            compn[(size_t)c * CSTR + (h0 + r) * 66 + (w0 + q)];
    }
    __syncthreads();

    int lane = tid & 63;
    int ij   = __builtin_amdgcn_readfirstlane(tid >> 6);  // force scalar
    int py = lane >> 3, pxx = lane & 7;

    const float* wb = ws + WR_F + (size_t)((ij * 5 + kt) * 64) * 48;

    float acc[5];
#pragma unroll
    for (int kk = 0; kk < 5; ++kk) acc[kk] = be[4 * (kt * 5 + kk) + ij];

#pragma unroll 2
    for (int c = 0; c < 64; ++c) {
        const float* cp = compT + c * 120 + py * 12 + pxx;
        float cv[9];
#pragma unroll
        for (int dy = 0; dy < 3; ++dy)
#pragma unroll
            for (int dx = 0; dx < 3; ++dx)
                cv[dy * 3 + dx] = cp[dy * 12 + dx];
        const float* w = wb + c * 48;                // uniform -> s_load
#pragma unroll
        for (int q = 0; q < 9; ++q) {
            float v = cv[q];
#pragma unroll
            for (int kk = 0; kk < 5; ++kk)
                acc[kk] += v * w[q * 5 + kk];        // v_fmac v, s, v
        }
    }

    float* lp = ws + LOG_F +
                (size_t)(n * 4096 + (h0 + py) * 64 + (w0 + pxx)) * 100 + ij;
#pragma unroll
    for (int kk = 0; kk < 5; ++kk) lp[4 * (kt * 5 + kk)] = acc[kk];
}

// ---------------- K2s v2: in-place softmax, LDS-coalesced ---------------
// grid 256 x 256thr: block handles 64 px. Global I/O as coalesced float4
// through LDS. Softmax thread-task = (pxl, ij); LDS reads at pxl*100+4k+ij
// are 2-way bank aliased max (100 mod 32 = 4) = free.
__global__ __launch_bounds__(256) void k2s_sm(float* __restrict__ ws) {
    __shared__ __align__(16) float L[64 * 100];  // 25600 B
    float* gp = ws + LOG_F + (size_t)blockIdx.x * 6400;
    int tid = threadIdx.x;

    for (int e4 = tid; e4 < 1600; e4 += 256)
        ((float4*)L)[e4] = ((const float4*)gp)[e4];
    __syncthreads();

    int pxl = tid >> 2, ij = tid & 3;
    float* p = L + pxl * 100 + ij;
    float m[25];
#pragma unroll
    for (int k = 0; k < 25; ++k) m[k] = p[4 * k];
    float mx = m[0];
#pragma unroll
    for (int k = 1; k < 25; ++k) mx = fmaxf(mx, m[k]);
    float ss = 0.f;
#pragma unroll
    for (int k = 0; k < 25; ++k) { m[k] = __expf(m[k] - mx); ss += m[k]; }
    float inv = 1.f / ss;
#pragma unroll
    for (int k = 0; k < 25; ++k) p[4 * k] = m[k] * inv;
    __syncthreads();

    for (int e4 = tid; e4 < 1600; e4 += 256)
        ((float4*)gp)[e4] = ((const float4*)L)[e4];
}

// ---------------- K3 v3: reassembly (masks pre-normalized) --------------
// grid 1024 x 256thr: b = cchunk*64 + tile. 16x16 px tile, 16-c chunk.
// x tile in LDS as [cg8][r20][q20][2] (channel pairs innermost, row stride
// 42 words): one ds_read_b64 per tap serves 2 channels, lanes contiguous
// 8B (conflict-free), tap offsets fold to immediates.
// Taps OUTER, channels inner: mask float4 is a per-tap transient; resident
// state is float2 A[8][4] = 64 VGPRs, statically indexed (no scratch).
// Plain launch_bounds(256) -- no min-waves hint (the hint caps VGPR at
// ~512/(2*arg) on this toolchain and forced spill in rounds 6/7).
__global__ __launch_bounds__(256) void k3_out(const float* __restrict__ x,
                                              const float* __restrict__ ws,
                                              float* __restrict__ out) {
    __shared__ __align__(16) float xt[8 * 20 * 42];  // 26880 B
    int b      = blockIdx.x;
    int tile   = b & 63;
    int cchunk = b >> 6;
    int n = tile >> 4, ty0 = ((tile >> 2) & 3) * 16, tx0 = (tile & 3) * 16;
    int c0 = cchunk * 16;

    int py = threadIdx.x >> 4, pxx = threadIdx.x & 15;
    int h = ty0 + py, w = tx0 + pxx;

    // stage x halo tile as float2 (halo col origin tx0-2 is even -> the
    // 20-wide row is 10 aligned float2s, all-or-nothing in bounds).
    const float* xn = x + (size_t)(n * 256 + c0) * 4096;
    for (int e2 = threadIdx.x; e2 < 3200; e2 += 256) {
        int c = e2 / 200, rem = e2 % 200, r = rem / 10, q2 = rem % 10;
        int hh = ty0 + r - 2, ww = tx0 + 2 * q2 - 2;
        float2 v = {0.f, 0.f};
        if (hh >= 0 && hh < 64 && ww >= 0 && ww < 64)
            v = *(const float2*)(xn + (size_t)c * 4096 + hh * 64 + ww);
        int a0 = (c >> 1) * 840 + r * 42 + 4 * q2 + (c & 1);
        xt[a0]     = v.x;
        xt[a0 + 2] = v.y;
    }
    __syncthreads();

    const float* lp = ws + LOG_F + (size_t)(n * 4096 + h * 64 + w) * 100;
    const float* vb = xt + py * 42 + pxx * 2;

    float2 A[8][4];
#pragma unroll
    for (int cg = 0; cg < 8; ++cg)
#pragma unroll
        for (int u = 0; u < 4; ++u) A[cg][u] = {0.f, 0.f};

    for (int dy = 0; dy < 5; ++dy) {
        const float4* mkp = (const float4*)lp + dy * 5;  // 5 taps this row
        const float* vrow = vb + dy * 42;
#pragma unroll
        for (int dx = 0; dx < 5; ++dx) {
            float4 mk = mkp[dx];                         // transient, L2-hot
#pragma unroll
            for (int cg = 0; cg < 8; ++cg) {
                float2 v = *(const float2*)(vrow + cg * 840 + dx * 2);
                A[cg][0].x += v.x * mk.x; A[cg][0].y += v.y * mk.x;
                A[cg][1].x += v.x * mk.y; A[cg][1].y += v.y * mk.y;
                A[cg][2].x += v.x * mk.z; A[cg][2].y += v.y * mk.z;
                A[cg][3].x += v.x * mk.w; A[cg][3].y += v.y * mk.w;
            }
        }
    }

#pragma unroll
    for (int cg = 0; cg < 8; ++cg) {
        int c = cg * 2;
        size_t ob0 = (((size_t)(n * 256 + c0 + c) * 128) + 2 * h) * 128 + 2 * w;
        float2 r0 = {A[cg][0].x, A[cg][1].x}, r1 = {A[cg][2].x, A[cg][3].x};
        *(float2*)(out + ob0)       = r0;
        *(float2*)(out + ob0 + 128) = r1;
        size_t ob1 = ob0 + 16384;
        float2 r2 = {A[cg][0].y, A[cg][1].y}, r3 = {A[cg][2].y, A[cg][3].y};
        *(float2*)(out + ob1)       = r2;
        *(float2*)(out + ob1 + 128) = r3;
    }
}

// ---------------- Fallback: fused kernel, fp32-only ---------------------
__global__ __launch_bounds__(256) void k_fused(const float* __restrict__ x,
                                               const float* __restrict__ Wc,
                                               const float* __restrict__ bc,
                                               const float* __restrict__ We,
                                               const float* __restrict__ be,
                                               float* __restrict__ out) {
    __shared__ float compS[64 * 101];
    int n = blockIdx.x >> 6, tile = blockIdx.x & 63;
    int ty0 = (tile >> 3) * 8, tx0 = (tile & 7) * 8;
    const float* xn = x + (size_t)n * 256 * 4096;
    {
        int pa = threadIdx.x & 127;
        int ga = __builtin_amdgcn_readfirstlane(threadIdx.x >> 7);
        bool act = pa < 100;
        int ah = ty0 + pa / 10 - 1, aw = tx0 + pa % 10 - 1;
        bool inb = act && ah >= 0 && ah < 64 && aw >= 0 && aw < 64;
        int xoff = ah * 64 + aw;
        float acc[32];
#pragma unroll
        for (int i = 0; i < 32; ++i) acc[i] = 0.f;
        for (int c = 0; c < 256; ++c) {
            float xv = inb ? xn[(size_t)c * 4096 + xoff] : 0.f;
#pragma unroll
            for (int i = 0; i < 32; ++i) acc[i] += xv * Wc[(ga * 32 + i) * 256 + c];
        }
        if (act)
#pragma unroll
            for (int i = 0; i < 32; ++i) {
                int cc = ga * 32 + i;
                compS[cc * 101 + pa] = inb ? acc[i] + bc[cc] : 0.f;
            }
    }
    __syncthreads();
    int px = threadIdx.x & 63;
    int ij = __builtin_amdgcn_readfirstlane(threadIdx.x >> 6);
    int py = px >> 3, pxx = px & 7;
    int h = ty0 + py, w = tx0 + pxx;
    float m[25];
#pragma unroll
    for (int k = 0; k < 25; ++k) m[k] = be[4 * k + ij];
    for (int cc = 0; cc < 64; ++cc) {
        float cv[9];
#pragma unroll
        for (int dy = 0; dy < 3; ++dy)
#pragma unroll
            for (int dx = 0; dx < 3; ++dx)
                cv[dy * 3 + dx] = compS[cc * 101 + (py + dy) * 10 + (pxx + dx)];
        int base = cc * 9;
#pragma unroll
        for (int k = 0; k < 25; ++k) {
            int eb = (4 * k + ij) * 576 + base;
            float s = 0.f;
#pragma unroll
            for (int qb = 0; qb < 9; ++qb) s += cv[qb] * We[eb + qb];
            m[k] += s;
        }
    }
    float mxv = m[0];
#pragma unroll
    for (int k = 1; k < 25; ++k) mxv = fmaxf(mxv, m[k]);
    float ss = 0.f;
#pragma unroll
    for (int k = 0; k < 25; ++k) { m[k] = __expf(m[k] - mxv); ss += m[k]; }
    float inv = 1.f / ss;
#pragma unroll
    for (int k = 0; k < 25; ++k) m[k] *= inv;
    int offs[25];
    unsigned vm = 0;
#pragma unroll
    for (int t = 0; t < 25; ++t) {
        int hh = h + t / 5 - 2, ww = w + t % 5 - 2;
        bool v = hh >= 0 && hh < 64 && ww >= 0 && ww < 64;
        offs[t] = v ? hh * 64 + ww : 0;
        if (v) vm |= 1u << t;
    }
    size_t outp = ((size_t)n * 256 * 128 + (2 * h + (ij >> 1))) * 128 + (2 * w + (ij & 1));
    for (int c = 0; c < 256; ++c) {
        const float* xc = xn + (size_t)c * 4096;
        float sum = 0.f;
#pragma unroll
        for (int t = 0; t < 25; ++t) {
            float v = ((vm >> t) & 1u) ? xc[offs[t]] : 0.f;
            sum += v * m[t];
        }
        out[outp + (size_t)c * 16384] = sum;
    }
}

extern "C" void kernel_launch(void* const* d_in, const int* in_sizes, int n_in,
                              void* d_out, int out_size, void* d_ws, size_t ws_size,
                              hipStream_t stream) {
    const float* x  = (const float*)d_in[0];
    const float* Wc = (const float*)d_in[1];
    const float* bc = (const float*)d_in[2];
    const float* We = (const float*)d_in[3];
    const float* be = (const float*)d_in[4];
    float* out = (float*)d_out;

    if (ws_size >= WS_NEED && d_ws != nullptr) {
        float* ws = (float*)d_ws;
        hipLaunchKernelGGL(k0_wr,   dim3(289),  dim3(256), 0, stream, We, Wc, ws);
        hipLaunchKernelGGL(k1_comp, dim3(512),  dim3(256), 0, stream, x, bc, ws);
        hipLaunchKernelGGL(k2_enc,  dim3(1280), dim3(256), 0, stream, be, ws);
        hipLaunchKernelGGL(k2s_sm,  dim3(256),  dim3(256), 0, stream, ws);
        hipLaunchKernelGGL(k3_out,  dim3(1024), dim3(256), 0, stream, x, ws, out);
    } else {
        hipLaunchKernelGGL(k_fused, dim3(256),  dim3(256), 0, stream,
                           x, Wc, bc, We, be, out);
    }
}

// Round 10
// 182.296 us; speedup vs baseline: 1.1881x; 1.0086x over previous
//
#include <hip/hip_runtime.h>
#include <hip/hip_bf16.h>

// CARAFE fp32 pipeline. x(4,256,64,64), Wc(64,256), bc(64), We(100,64,3,3),
// be(100) -> out(4,256,128,128). SF=2 K=5 G=1 CC=64 EK=3. All I/O fp32.
//
// ws layout (fp32 elements):
//   comp  [4][64][66*66]   zero-padded halo   @ 0          (1,115,136)
//   Wr2   [ij4][kt5][cc64][48]  q*5+kk packed @ 1,115,136  (61,440 of 64,512)
//   logit [16384 px][100]  e = 4k+ij          @ 1,179,648  (1,638,400)
//     NB: first 16,384 floats of logit double as WcT[c256][cc64] during
//     k0->k1 (dead space until k2 writes logits; stream-serialized).
// total 11,272,192 B. Host-gated on ws_size; fallback = fused kernel.
//
// Round 13 (this round): k2 v6 = v3 + LANE REMAP ONLY. Round-12 counters:
// k2 6.15M conflicts / 2.95M ds_reads = +2.1 cyc/read. Diagnosis: with
// py=lane>>3, a 32-lane phase hits banks {py*12+pxx} = {0-7,12-19,24-31,
// 4-11}: banks 4-7 doubled, 20-23 idle -> 2-way in-phase serialization.
// Fix: py=lane&7, pxx=lane>>3 -> phase banks (lane&7)*12+(lane>>3) =
// {0,12,24,4,16,28,8,20}+{0..3} = all 32 exactly once. Zero conflicts,
// zero structural change (grid/LDS/weights/staging identical).

#define COMP_F 0
#define WR_F   1115136
#define LOG_F  1179648
#define WS_NEED 11272192ull
#define CSTR 4356  // 66*66 comp per-channel stride

// ---------------- K0: Wr2 repack + WcT transpose ------------------------
// job1 (tid < 57600): We(100,576) -> Wr2[ij][kt][cc][48], row = q*5+kk.
// job2 (tid >= 57600): Wc(64,256) -> WcT[c][cc] @ LOG_F (16,384 floats).
__global__ void k0_wr(const float* __restrict__ We, const float* __restrict__ Wc,
                      float* __restrict__ ws) {
    int tid = blockIdx.x * blockDim.x + threadIdx.x;
    if (tid < 57600) {
        int kk = tid % 5;
        int q  = (tid / 5) % 9;
        int cc = (tid / 45) % 64;
        int kt = (tid / 2880) % 5;
        int ij = tid / 14400;
        ws[WR_F + (size_t)(((ij * 5 + kt) * 64 + cc)) * 48 + q * 5 + kk] =
            We[(size_t)(4 * (kt * 5 + kk) + ij) * 576 + cc * 9 + q];
    } else if (tid < 57600 + 16384) {
        int t2 = tid - 57600;
        int c = t2 >> 6, cc = t2 & 63;
        ws[LOG_F + t2] = Wc[cc * 256 + c];
    }
}

// ---------------- K1 v3: 1x1 compressor 256->64, padded comp out --------
// grid 512 = ccq*64 + pxtile; block 256thr; thread = one pixel, 8 cc.
// Weights from WcT (contiguous 32B/c -> s_load_dwordx8). x loads coalesced
// (256 consecutive px per block). 2 blocks/CU = 2 waves/SIMD.
__global__ __launch_bounds__(256) void k1_comp(const float* __restrict__ x,
                                               const float* __restrict__ bc,
                                               float* __restrict__ ws) {
    int b      = blockIdx.x;
    int pxtile = b & 63;       // 0..63 ; b%8 = pxtile%8 -> cc-siblings same XCD
    int ccq    = b >> 6;       // 0..7, wave-uniform
    int tid = threadIdx.x;
    int n   = pxtile >> 4;
    int off = (pxtile & 15) * 256 + tid;   // 0..4095 within image
    int h = off >> 6, w = off & 63;
    int cc0 = ccq * 8;

    const float* wT = ws + LOG_F;          // WcT[c][64]
    const float* xp = x + (size_t)n * 256 * 4096 + off;

    float acc[8];
#pragma unroll
    for (int u = 0; u < 8; ++u) acc[u] = 0.f;

#pragma unroll 8
    for (int c = 0; c < 256; ++c) {
        float xv = xp[(size_t)c * 4096];
        const float* wr = wT + c * 64 + cc0;   // uniform -> s_load_dwordx8
#pragma unroll
        for (int u = 0; u < 8; ++u) acc[u] += xv * wr[u];
    }

    float* compb = ws + COMP_F + (size_t)(n * 64 + cc0) * CSTR;
#pragma unroll
    for (int u = 0; u < 8; ++u) {
        float* cb_ = compb + (size_t)u * CSTR;
        cb_[(h + 1) * 66 + (w + 1)] = acc[u] + bc[cc0 + u];
        // zero halo border (pad=1 of the 3x3 conv)
        if (w < 2) cb_[(h + 1) * 66 + (w ? 65 : 0)] = 0.f;
        if (h == 0)  { cb_[w] = 0.f;           if (w < 2) cb_[64 + w] = 0.f; }
        if (h == 63) { cb_[65 * 66 + w] = 0.f; if (w < 2) cb_[65 * 66 + 64 + w] = 0.f; }
    }
}

// ---------------- K2 v6: 3x3 encoder -> raw logits ----------------------
// v3 + lane remap. grid 1280 = kt*256 + tile; block 256 thr = 4 ij-waves.
// comp 8x8 tile + halo in LDS, row stride 12. py=lane&7, pxx=lane>>3:
// per-phase banks (lane&7)*12+(lane>>3) cover all 32 exactly once ->
// conflict-free (v3's py=lane>>3 doubled banks 4-7/20-23: 6.15M conflicts).
// Weights via wave-uniform addresses -> s_load/SGPR (SMEM pipe).
__global__ __launch_bounds__(256, 5) void k2_enc(const float* __restrict__ be,
                                                 float* __restrict__ ws) {
    __shared__ __align__(16) float compT[64 * 120];  // 30720 B
    int b    = blockIdx.x;
    int tile = b & 255;                              // low bits: same-tile
    int kt   = b >> 8;                               // 0..4, siblings same XCD
    int n = tile >> 6, th = (tile >> 3) & 7, tw = tile & 7;
    int h0 = th * 8, w0 = tw * 8;
    int tid = threadIdx.x;

    const float* compn = ws + COMP_F + (size_t)n * 64 * CSTR;
    // stage comp halo tile: compT[c*120 + r*12 + q] = comp[c][h0+r][w0+q]
    for (int e = tid; e < 6400; e += 256) {
        int c = e / 100, rq = e % 100, r = rq / 10, q = rq % 10;
        compT[c * 120 + r * 12 + q] =
            compn[(size_t)c * CSTR + (h0 + r) * 66 + (w0 + q)];
    }
    __syncthreads();

    int lane = tid & 63;
    int ij   = __builtin_amdgcn_readfirstlane(tid >> 6);  // force scalar
    int py = lane & 7, pxx = lane >> 3;   // REMAP: conflict-free bank walk

    const float* wb = ws + WR_F + (size_t)((ij * 5 + kt) * 64) * 48;

    float acc[5];
#pragma unroll
    for (int kk = 0; kk < 5; ++kk) acc[kk] = be[4 * (kt * 5 + kk) + ij];

#pragma unroll 2
    for (int c = 0; c < 64; ++c) {
        const float* cp = compT + c * 120 + py * 12 + pxx;
        float cv[9];
#pragma unroll
        for (int dy = 0; dy < 3; ++dy)
#pragma unroll
            for (int dx = 0; dx < 3; ++dx)
                cv[dy * 3 + dx] = cp[dy * 12 + dx];
        const float* w = wb + c * 48;                // uniform -> s_load
#pragma unroll
        for (int q = 0; q < 9; ++q) {
            float v = cv[q];
#pragma unroll
            for (int kk = 0; kk < 5; ++kk)
                acc[kk] += v * w[q * 5 + kk];        // v_fmac v, s, v
        }
    }

    float* lp = ws + LOG_F +
                (size_t)(n * 4096 + (h0 + py) * 64 + (w0 + pxx)) * 100 + ij;
#pragma unroll
    for (int kk = 0; kk < 5; ++kk) lp[4 * (kt * 5 + kk)] = acc[kk];
}

// ---------------- K2s v2: in-place softmax, LDS-coalesced ---------------
// grid 256 x 256thr: block handles 64 px. Global I/O as coalesced float4
// through LDS. Softmax thread-task = (pxl, ij); LDS reads at pxl*100+4k+ij
// are 2-way bank aliased max (100 mod 32 = 4) = free.
__global__ __launch_bounds__(256) void k2s_sm(float* __restrict__ ws) {
    __shared__ __align__(16) float L[64 * 100];  // 25600 B
    float* gp = ws + LOG_F + (size_t)blockIdx.x * 6400;
    int tid = threadIdx.x;

    for (int e4 = tid; e4 < 1600; e4 += 256)
        ((float4*)L)[e4] = ((const float4*)gp)[e4];
    __syncthreads();

    int pxl = tid >> 2, ij = tid & 3;
    float* p = L + pxl * 100 + ij;
    float m[25];
#pragma unroll
    for (int k = 0; k < 25; ++k) m[k] = p[4 * k];
    float mx = m[0];
#pragma unroll
    for (int k = 1; k < 25; ++k) mx = fmaxf(mx, m[k]);
    float ss = 0.f;
#pragma unroll
    for (int k = 0; k < 25; ++k) { m[k] = __expf(m[k] - mx); ss += m[k]; }
    float inv = 1.f / ss;
#pragma unroll
    for (int k = 0; k < 25; ++k) p[4 * k] = m[k] * inv;
    __syncthreads();

    for (int e4 = tid; e4 < 1600; e4 += 256)
        ((float4*)gp)[e4] = ((const float4*)L)[e4];
}

// ---------------- K3 v3: reassembly (masks pre-normalized) --------------
// grid 1024 x 256thr: b = cchunk*64 + tile. 16x16 px tile, 16-c chunk.
// x tile in LDS as [cg8][r20][q20][2] (channel pairs innermost, row stride
// 42 words): one ds_read_b64 per tap serves 2 channels, lanes contiguous
// 8B (conflict-free), tap offsets fold to immediates.
// Taps OUTER, channels inner: mask float4 is a per-tap transient; resident
// state is float2 A[8][4] = 64 VGPRs, statically indexed (no scratch).
// Plain launch_bounds(256) -- no min-waves hint (the hint caps VGPR at
// ~512/(2*arg) on this toolchain and forced spill in rounds 6/7).
__global__ __launch_bounds__(256) void k3_out(const float* __restrict__ x,
                                              const float* __restrict__ ws,
                                              float* __restrict__ out) {
    __shared__ __align__(16) float xt[8 * 20 * 42];  // 26880 B
    int b      = blockIdx.x;
    int tile   = b & 63;
    int cchunk = b >> 6;
    int n = tile >> 4, ty0 = ((tile >> 2) & 3) * 16, tx0 = (tile & 3) * 16;
    int c0 = cchunk * 16;

    int py = threadIdx.x >> 4, pxx = threadIdx.x & 15;
    int h = ty0 + py, w = tx0 + pxx;

    // stage x halo tile as float2 (halo col origin tx0-2 is even -> the
    // 20-wide row is 10 aligned float2s, all-or-nothing in bounds).
    const float* xn = x + (size_t)(n * 256 + c0) * 4096;
    for (int e2 = threadIdx.x; e2 < 3200; e2 += 256) {
        int c = e2 / 200, rem = e2 % 200, r = rem / 10, q2 = rem % 10;
        int hh = ty0 + r - 2, ww = tx0 + 2 * q2 - 2;
        float2 v = {0.f, 0.f};
        if (hh >= 0 && hh < 64 && ww >= 0 && ww < 64)
            v = *(const float2*)(xn + (size_t)c * 4096 + hh * 64 + ww);
        int a0 = (c >> 1) * 840 + r * 42 + 4 * q2 + (c & 1);
        xt[a0]     = v.x;
        xt[a0 + 2] = v.y;
    }
    __syncthreads();

    const float* lp = ws + LOG_F + (size_t)(n * 4096 + h * 64 + w) * 100;
    const float* vb = xt + py * 42 + pxx * 2;

    float2 A[8][4];
#pragma unroll
    for (int cg = 0; cg < 8; ++cg)
#pragma unroll
        for (int u = 0; u < 4; ++u) A[cg][u] = {0.f, 0.f};

    for (int dy = 0; dy < 5; ++dy) {
        const float4* mkp = (const float4*)lp + dy * 5;  // 5 taps this row
        const float* vrow = vb + dy * 42;
#pragma unroll
        for (int dx = 0; dx < 5; ++dx) {
            float4 mk = mkp[dx];                         // transient, L2-hot
#pragma unroll
            for (int cg = 0; cg < 8; ++cg) {
                float2 v = *(const float2*)(vrow + cg * 840 + dx * 2);
                A[cg][0].x += v.x * mk.x; A[cg][0].y += v.y * mk.x;
                A[cg][1].x += v.x * mk.y; A[cg][1].y += v.y * mk.y;
                A[cg][2].x += v.x * mk.z; A[cg][2].y += v.y * mk.z;
                A[cg][3].x += v.x * mk.w; A[cg][3].y += v.y * mk.w;
            }
        }
    }

#pragma unroll
    for (int cg = 0; cg < 8; ++cg) {
        int c = cg * 2;
        size_t ob0 = (((size_t)(n * 256 + c0 + c) * 128) + 2 * h) * 128 + 2 * w;
        float2 r0 = {A[cg][0].x, A[cg][1].x}, r1 = {A[cg][2].x, A[cg][3].x};
        *(float2*)(out + ob0)       = r0;
        *(float2*)(out + ob0 + 128) = r1;
        size_t ob1 = ob0 + 16384;
        float2 r2 = {A[cg][0].y, A[cg][1].y}, r3 = {A[cg][2].y, A[cg][3].y};
        *(float2*)(out + ob1)       = r2;
        *(float2*)(out + ob1 + 128) = r3;
    }
}

// ---------------- Fallback: fused kernel, fp32-only ---------------------
__global__ __launch_bounds__(256) void k_fused(const float* __restrict__ x,
                                               const float* __restrict__ Wc,
                                               const float* __restrict__ bc,
                                               const float* __restrict__ We,
                                               const float* __restrict__ be,
                                               float* __restrict__ out) {
    __shared__ float compS[64 * 101];
    int n = blockIdx.x >> 6, tile = blockIdx.x & 63;
    int ty0 = (tile >> 3) * 8, tx0 = (tile & 7) * 8;
    const float* xn = x + (size_t)n * 256 * 4096;
    {
        int pa = threadIdx.x & 127;
        int ga = __builtin_amdgcn_readfirstlane(threadIdx.x >> 7);
        bool act = pa < 100;
        int ah = ty0 + pa / 10 - 1, aw = tx0 + pa % 10 - 1;
        bool inb = act && ah >= 0 && ah < 64 && aw >= 0 && aw < 64;
        int xoff = ah * 64 + aw;
        float acc[32];
#pragma unroll
        for (int i = 0; i < 32; ++i) acc[i] = 0.f;
        for (int c = 0; c < 256; ++c) {
            float xv = inb ? xn[(size_t)c * 4096 + xoff] : 0.f;
#pragma unroll
            for (int i = 0; i < 32; ++i) acc[i] += xv * Wc[(ga * 32 + i) * 256 + c];
        }
        if (act)
#pragma unroll
            for (int i = 0; i < 32; ++i) {
                int cc = ga * 32 + i;
                compS[cc * 101 + pa] = inb ? acc[i] + bc[cc] : 0.f;
            }
    }
    __syncthreads();
    int px = threadIdx.x & 63;
    int ij = __builtin_amdgcn_readfirstlane(threadIdx.x >> 6);
    int py = px >> 3, pxx = px & 7;
    int h = ty0 + py, w = tx0 + pxx;
    float m[25];
#pragma unroll
    for (int k = 0; k < 25; ++k) m[k] = be[4 * k + ij];
    for (int cc = 0; cc < 64; ++cc) {
        float cv[9];
#pragma unroll
        for (int dy = 0; dy < 3; ++dy)
#pragma unroll
            for (int dx = 0; dx < 3; ++dx)
                cv[dy * 3 + dx] = compS[cc * 101 + (py + dy) * 10 + (pxx + dx)];
        int base = cc * 9;
#pragma unroll
        for (int k = 0; k < 25; ++k) {
            int eb = (4 * k + ij) * 576 + base;
            float s = 0.f;
#pragma unroll
            for (int qb = 0; qb < 9; ++qb) s += cv[qb] * We[eb + qb];
            m[k] += s;
        }
    }
    float mxv = m[0];
#pragma unroll
    for (int k = 1; k < 25; ++k) mxv = fmaxf(mxv, m[k]);
    float ss = 0.f;
#pragma unroll
    for (int k = 0; k < 25; ++k) { m[k] = __expf(m[k] - mxv); ss += m[k]; }
    float inv = 1.f / ss;
#pragma unroll
    for (int k = 0; k < 25; ++k) m[k] *= inv;
    int offs[25];
    unsigned vm = 0;
#pragma unroll
    for (int t = 0; t < 25; ++t) {
        int hh = h + t / 5 - 2, ww = w + t % 5 - 2;
        bool v = hh >= 0 && hh < 64 && ww >= 0 && ww < 64;
        offs[t] = v ? hh * 64 + ww : 0;
        if (v) vm |= 1u << t;
    }
    size_t outp = ((size_t)n * 256 * 128 + (2 * h + (ij >> 1))) * 128 + (2 * w + (ij & 1));
    for (int c = 0; c < 256; ++c) {
        const float* xc = xn + (size_t)c * 4096;
        float sum = 0.f;
#pragma unroll
        for (int t = 0; t < 25; ++t) {
            float v = ((vm >> t) & 1u) ? xc[offs[t]] : 0.f;
            sum += v * m[t];
        }
        out[outp + (size_t)c * 16384] = sum;
    }
}

extern "C" void kernel_launch(void* const* d_in, const int* in_sizes, int n_in,
                              void* d_out, int out_size, void* d_ws, size_t ws_size,
                              hipStream_t stream) {
    const float* x  = (const float*)d_in[0];
    const float* Wc = (const float*)d_in[1];
    const float* bc = (const float*)d_in[2];
    const float* We = (const float*)d_in[3];
    const float* be = (const float*)d_in[4];
    float* out = (float*)d_out;

    if (ws_size >= WS_NEED && d_ws != nullptr) {
        float* ws = (float*)d_ws;
        hipLaunchKernelGGL(k0_wr,   dim3(289),  dim3(256), 0, stream, We, Wc, ws);
        hipLaunchKernelGGL(k1_comp, dim3(512),  dim3(256), 0, stream, x, bc, ws);
        hipLaunchKernelGGL(k2_enc,  dim3(1280), dim3(256), 0, stream, be, ws);
        hipLaunchKernelGGL(k2s_sm,  dim3(256),  dim3(256), 0, stream, ws);
        hipLaunchKernelGGL(k3_out,  dim3(1024), dim3(256), 0, stream, x, ws, out);
    } else {
        hipLaunchKernelGGL(k_fused, dim3(256),  dim3(256), 0, stream,
                           x, Wc, bc, We, be, out);
    }
}

// Round 11
// 177.260 us; speedup vs baseline: 1.2218x; 1.0284x over previous
//
#include <hip/hip_runtime.h>
#include <hip/hip_bf16.h>

// CARAFE fp32 pipeline. x(4,256,64,64), Wc(64,256), bc(64), We(100,64,3,3),
// be(100) -> out(4,256,128,128). SF=2 K=5 G=1 CC=64 EK=3. All I/O fp32.
//
// ws layout (fp32 elements):
//   comp  [4][64][66*66]   zero-padded halo   @ 0          (1,115,136)
//   Wr2   [ij4][kt5][cc64][48]  q*5+kk packed @ 1,115,136  (61,440 of 64,512)
//   logit [16384 px][100]  e = 4k+ij          @ 1,179,648  (1,638,400)
//     NB: first 16,384 floats of logit double as WcT[c256][cc64] during
//     k0->k1 (dead space until k2 writes logits; stream-serialized).
// total 11,272,192 B. Host-gated on ws_size; fallback = fused kernel.
//
// Round 14 (this round): RESTRICT-SPLIT the ws regions into separate kernel
// args. Round-13 A/B: conflicts 6.15M->0.26M yet dur unchanged 48.6->49.4
// -> DS was never the limiter. VALUBusy 44% of 118k cyc = ~52k VALU-issue
// per SIMD vs 28.8k modeled FMA -> ~2x instruction stream. Diagnosis: k2
// reads weights and writes logits through the SAME ws pointer; compiler
// can't prove no-alias -> uniform weight loads lower to per-lane VMEM
// global_load (+v_mov), ~2880 VMEM wave-instrs/wave, not s_load. Fix:
// pass comp/wr/logits (and k1's wT/comp) as DISTINCT __restrict__ args ->
// true s_load_dwordx16 + v_fmac v,s,v. No algorithmic change anywhere.

#define COMP_F 0
#define WR_F   1115136
#define LOG_F  1179648
#define WS_NEED 11272192ull
#define CSTR 4356  // 66*66 comp per-channel stride

// ---------------- K0: Wr2 repack + WcT transpose ------------------------
// job1 (tid < 57600): We(100,576) -> Wr2[ij][kt][cc][48], row = q*5+kk.
// job2 (tid >= 57600): Wc(64,256) -> WcT[c][cc] @ LOG_F (16,384 floats).
__global__ void k0_wr(const float* __restrict__ We, const float* __restrict__ Wc,
                      float* __restrict__ ws) {
    int tid = blockIdx.x * blockDim.x + threadIdx.x;
    if (tid < 57600) {
        int kk = tid % 5;
        int q  = (tid / 5) % 9;
        int cc = (tid / 45) % 64;
        int kt = (tid / 2880) % 5;
        int ij = tid / 14400;
        ws[WR_F + (size_t)(((ij * 5 + kt) * 64 + cc)) * 48 + q * 5 + kk] =
            We[(size_t)(4 * (kt * 5 + kk) + ij) * 576 + cc * 9 + q];
    } else if (tid < 57600 + 16384) {
        int t2 = tid - 57600;
        int c = t2 >> 6, cc = t2 & 63;
        ws[LOG_F + t2] = Wc[cc * 256 + c];
    }
}

// ---------------- K1 v4: 1x1 compressor 256->64, padded comp out --------
// grid 512 = ccq*64 + pxtile; block 256thr; thread = one pixel, 8 cc.
// wT/comp now separate restrict args -> weight loads are TRUE s_loads
// (with the single-ws version the compiler couldn't prove no-alias vs the
// comp stores and fell back to per-lane VMEM).
__global__ __launch_bounds__(256) void k1_comp(const float* __restrict__ x,
                                               const float* __restrict__ bc,
                                               const float* __restrict__ wT,
                                               float* __restrict__ comp) {
    int b      = blockIdx.x;
    int pxtile = b & 63;       // 0..63 ; b%8 = pxtile%8 -> cc-siblings same XCD
    int ccq    = b >> 6;       // 0..7, wave-uniform
    int tid = threadIdx.x;
    int n   = pxtile >> 4;
    int off = (pxtile & 15) * 256 + tid;   // 0..4095 within image
    int h = off >> 6, w = off & 63;
    int cc0 = ccq * 8;

    const float* xp = x + (size_t)n * 256 * 4096 + off;

    float acc[8];
#pragma unroll
    for (int u = 0; u < 8; ++u) acc[u] = 0.f;

#pragma unroll 8
    for (int c = 0; c < 256; ++c) {
        float xv = xp[(size_t)c * 4096];
        const float* wr = wT + c * 64 + cc0;   // uniform -> s_load_dwordx8
#pragma unroll
        for (int u = 0; u < 8; ++u) acc[u] += xv * wr[u];
    }

    float* compb = comp + (size_t)(n * 64 + cc0) * CSTR;
#pragma unroll
    for (int u = 0; u < 8; ++u) {
        float* cb_ = compb + (size_t)u * CSTR;
        cb_[(h + 1) * 66 + (w + 1)] = acc[u] + bc[cc0 + u];
        // zero halo border (pad=1 of the 3x3 conv)
        if (w < 2) cb_[(h + 1) * 66 + (w ? 65 : 0)] = 0.f;
        if (h == 0)  { cb_[w] = 0.f;           if (w < 2) cb_[64 + w] = 0.f; }
        if (h == 63) { cb_[65 * 66 + w] = 0.f; if (w < 2) cb_[65 * 66 + 64 + w] = 0.f; }
    }
}

// ---------------- K2 v7: 3x3 encoder -> raw logits ----------------------
// = v6 (lane-remapped, conflict-free) + restrict-split args. comp (read),
// wr (read, uniform -> s_load), logits (write) are disjoint restrict
// pointers so the SMEM path is finally provable. grid 1280 = kt*256+tile;
// block 256 thr = 4 ij-waves; comp 8x8+halo tile in LDS, stride 12.
__global__ __launch_bounds__(256, 5) void k2_enc(const float* __restrict__ be,
                                                 const float* __restrict__ comp,
                                                 const float* __restrict__ wr,
                                                 float* __restrict__ logits) {
    __shared__ __align__(16) float compT[64 * 120];  // 30720 B
    int b    = blockIdx.x;
    int tile = b & 255;                              // low bits: same-tile
    int kt   = b >> 8;                               // 0..4, siblings same XCD
    int n = tile >> 6, th = (tile >> 3) & 7, tw = tile & 7;
    int h0 = th * 8, w0 = tw * 8;
    int tid = threadIdx.x;

    const float* compn = comp + (size_t)n * 64 * CSTR;
    // stage comp halo tile: compT[c*120 + r*12 + q] = comp[c][h0+r][w0+q]
    for (int e = tid; e < 6400; e += 256) {
        int c = e / 100, rq = e % 100, r = rq / 10, q = rq % 10;
        compT[c * 120 + r * 12 + q] =
            compn[(size_t)c * CSTR + (h0 + r) * 66 + (w0 + q)];
    }
    __syncthreads();

    int lane = tid & 63;
    int ij   = __builtin_amdgcn_readfirstlane(tid >> 6);  // force scalar
    int py = lane & 7, pxx = lane >> 3;   // conflict-free bank walk (r13)

    const float* wb = wr + (size_t)((ij * 5 + kt) * 64) * 48;

    float acc[5];
#pragma unroll
    for (int kk = 0; kk < 5; ++kk) acc[kk] = be[4 * (kt * 5 + kk) + ij];

#pragma unroll 2
    for (int c = 0; c < 64; ++c) {
        const float* cp = compT + c * 120 + py * 12 + pxx;
        float cv[9];
#pragma unroll
        for (int dy = 0; dy < 3; ++dy)
#pragma unroll
            for (int dx = 0; dx < 3; ++dx)
                cv[dy * 3 + dx] = cp[dy * 12 + dx];
        const float* w = wb + c * 48;                // uniform -> s_load
#pragma unroll
        for (int q = 0; q < 9; ++q) {
            float v = cv[q];
#pragma unroll
            for (int kk = 0; kk < 5; ++kk)
                acc[kk] += v * w[q * 5 + kk];        // v_fmac v, s, v
        }
    }

    float* lp = logits +
                (size_t)(n * 4096 + (h0 + py) * 64 + (w0 + pxx)) * 100 + ij;
#pragma unroll
    for (int kk = 0; kk < 5; ++kk) lp[4 * (kt * 5 + kk)] = acc[kk];
}

// ---------------- K2s v2: in-place softmax, LDS-coalesced ---------------
// grid 256 x 256thr: block handles 64 px. Global I/O as coalesced float4
// through LDS. Softmax thread-task = (pxl, ij); LDS reads at pxl*100+4k+ij
// are 2-way bank aliased max (100 mod 32 = 4) = free.
__global__ __launch_bounds__(256) void k2s_sm(float* __restrict__ logits) {
    __shared__ __align__(16) float L[64 * 100];  // 25600 B
    float* gp = logits + (size_t)blockIdx.x * 6400;
    int tid = threadIdx.x;

    for (int e4 = tid; e4 < 1600; e4 += 256)
        ((float4*)L)[e4] = ((const float4*)gp)[e4];
    __syncthreads();

    int pxl = tid >> 2, ij = tid & 3;
    float* p = L + pxl * 100 + ij;
    float m[25];
#pragma unroll
    for (int k = 0; k < 25; ++k) m[k] = p[4 * k];
    float mx = m[0];
#pragma unroll
    for (int k = 1; k < 25; ++k) mx = fmaxf(mx, m[k]);
    float ss = 0.f;
#pragma unroll
    for (int k = 0; k < 25; ++k) { m[k] = __expf(m[k] - mx); ss += m[k]; }
    float inv = 1.f / ss;
#pragma unroll
    for (int k = 0; k < 25; ++k) p[4 * k] = m[k] * inv;
    __syncthreads();

    for (int e4 = tid; e4 < 1600; e4 += 256)
        ((float4*)gp)[e4] = ((const float4*)L)[e4];
}

// ---------------- K3 v4: reassembly (masks pre-normalized) --------------
// grid 1024 x 256thr: b = cchunk*64 + tile. 16x16 px tile, 16-c chunk.
// x tile in LDS as [cg8][r20][q20][2]; one ds_read_b64 per tap serves 2
// channels. Taps OUTER, channels inner; resident float2 A[8][4] (64 VGPR,
// statically indexed). logits now a separate const restrict arg.
__global__ __launch_bounds__(256) void k3_out(const float* __restrict__ x,
                                              const float* __restrict__ logits,
                                              float* __restrict__ out) {
    __shared__ __align__(16) float xt[8 * 20 * 42];  // 26880 B
    int b      = blockIdx.x;
    int tile   = b & 63;
    int cchunk = b >> 6;
    int n = tile >> 4, ty0 = ((tile >> 2) & 3) * 16, tx0 = (tile & 3) * 16;
    int c0 = cchunk * 16;

    int py = threadIdx.x >> 4, pxx = threadIdx.x & 15;
    int h = ty0 + py, w = tx0 + pxx;

    // stage x halo tile as float2 (halo col origin tx0-2 is even -> the
    // 20-wide row is 10 aligned float2s, all-or-nothing in bounds).
    const float* xn = x + (size_t)(n * 256 + c0) * 4096;
    for (int e2 = threadIdx.x; e2 < 3200; e2 += 256) {
        int c = e2 / 200, rem = e2 % 200, r = rem / 10, q2 = rem % 10;
        int hh = ty0 + r - 2, ww = tx0 + 2 * q2 - 2;
        float2 v = {0.f, 0.f};
        if (hh >= 0 && hh < 64 && ww >= 0 && ww < 64)
            v = *(const float2*)(xn + (size_t)c * 4096 + hh * 64 + ww);
        int a0 = (c >> 1) * 840 + r * 42 + 4 * q2 + (c & 1);
        xt[a0]     = v.x;
        xt[a0 + 2] = v.y;
    }
    __syncthreads();

    const float* lp = logits + (size_t)(n * 4096 + h * 64 + w) * 100;
    const float* vb = xt + py * 42 + pxx * 2;

    float2 A[8][4];
#pragma unroll
    for (int cg = 0; cg < 8; ++cg)
#pragma unroll
        for (int u = 0; u < 4; ++u) A[cg][u] = {0.f, 0.f};

    for (int dy = 0; dy < 5; ++dy) {
        const float4* mkp = (const float4*)lp + dy * 5;  // 5 taps this row
        const float* vrow = vb + dy * 42;
#pragma unroll
        for (int dx = 0; dx < 5; ++dx) {
            float4 mk = mkp[dx];                         // transient, L2-hot
#pragma unroll
            for (int cg = 0; cg < 8; ++cg) {
                float2 v = *(const float2*)(vrow + cg * 840 + dx * 2);
                A[cg][0].x += v.x * mk.x; A[cg][0].y += v.y * mk.x;
                A[cg][1].x += v.x * mk.y; A[cg][1].y += v.y * mk.y;
                A[cg][2].x += v.x * mk.z; A[cg][2].y += v.y * mk.z;
                A[cg][3].x += v.x * mk.w; A[cg][3].y += v.y * mk.w;
            }
        }
    }

#pragma unroll
    for (int cg = 0; cg < 8; ++cg) {
        int c = cg * 2;
        size_t ob0 = (((size_t)(n * 256 + c0 + c) * 128) + 2 * h) * 128 + 2 * w;
        float2 r0 = {A[cg][0].x, A[cg][1].x}, r1 = {A[cg][2].x, A[cg][3].x};
        *(float2*)(out + ob0)       = r0;
        *(float2*)(out + ob0 + 128) = r1;
        size_t ob1 = ob0 + 16384;
        float2 r2 = {A[cg][0].y, A[cg][1].y}, r3 = {A[cg][2].y, A[cg][3].y};
        *(float2*)(out + ob1)       = r2;
        *(float2*)(out + ob1 + 128) = r3;
    }
}

// ---------------- Fallback: fused kernel, fp32-only ---------------------
__global__ __launch_bounds__(256) void k_fused(const float* __restrict__ x,
                                               const float* __restrict__ Wc,
                                               const float* __restrict__ bc,
                                               const float* __restrict__ We,
                                               const float* __restrict__ be,
                                               float* __restrict__ out) {
    __shared__ float compS[64 * 101];
    int n = blockIdx.x >> 6, tile = blockIdx.x & 63;
    int ty0 = (tile >> 3) * 8, tx0 = (tile & 7) * 8;
    const float* xn = x + (size_t)n * 256 * 4096;
    {
        int pa = threadIdx.x & 127;
        int ga = __builtin_amdgcn_readfirstlane(threadIdx.x >> 7);
        bool act = pa < 100;
        int ah = ty0 + pa / 10 - 1, aw = tx0 + pa % 10 - 1;
        bool inb = act && ah >= 0 && ah < 64 && aw >= 0 && aw < 64;
        int xoff = ah * 64 + aw;
        float acc[32];
#pragma unroll
        for (int i = 0; i < 32; ++i) acc[i] = 0.f;
        for (int c = 0; c < 256; ++c) {
            float xv = inb ? xn[(size_t)c * 4096 + xoff] : 0.f;
#pragma unroll
            for (int i = 0; i < 32; ++i) acc[i] += xv * Wc[(ga * 32 + i) * 256 + c];
        }
        if (act)
#pragma unroll
            for (int i = 0; i < 32; ++i) {
                int cc = ga * 32 + i;
                compS[cc * 101 + pa] = inb ? acc[i] + bc[cc] : 0.f;
            }
    }
    __syncthreads();
    int px = threadIdx.x & 63;
    int ij = __builtin_amdgcn_readfirstlane(threadIdx.x >> 6);
    int py = px >> 3, pxx = px & 7;
    int h = ty0 + py, w = tx0 + pxx;
    float m[25];
#pragma unroll
    for (int k = 0; k < 25; ++k) m[k] = be[4 * k + ij];
    for (int cc = 0; cc < 64; ++cc) {
        float cv[9];
#pragma unroll
        for (int dy = 0; dy < 3; ++dy)
#pragma unroll
            for (int dx = 0; dx < 3; ++dx)
                cv[dy * 3 + dx] = compS[cc * 101 + (py + dy) * 10 + (pxx + dx)];
        int base = cc * 9;
#pragma unroll
        for (int k = 0; k < 25; ++k) {
            int eb = (4 * k + ij) * 576 + base;
            float s = 0.f;
#pragma unroll
            for (int qb = 0; qb < 9; ++qb) s += cv[qb] * We[eb + qb];
            m[k] += s;
        }
    }
    float mxv = m[0];
#pragma unroll
    for (int k = 1; k < 25; ++k) mxv = fmaxf(mxv, m[k]);
    float ss = 0.f;
#pragma unroll
    for (int k = 0; k < 25; ++k) { m[k] = __expf(m[k] - mxv); ss += m[k]; }
    float inv = 1.f / ss;
#pragma unroll
    for (int k = 0; k < 25; ++k) m[k] *= inv;
    int offs[25];
    unsigned vm = 0;
#pragma unroll
    for (int t = 0; t < 25; ++t) {
        int hh = h + t / 5 - 2, ww = w + t % 5 - 2;
        bool v = hh >= 0 && hh < 64 && ww >= 0 && ww < 64;
        offs[t] = v ? hh * 64 + ww : 0;
        if (v) vm |= 1u << t;
    }
    size_t outp = ((size_t)n * 256 * 128 + (2 * h + (ij >> 1))) * 128 + (2 * w + (ij & 1));
    for (int c = 0; c < 256; ++c) {
        const float* xc = xn + (size_t)c * 4096;
        float sum = 0.f;
#pragma unroll
        for (int t = 0; t < 25; ++t) {
            float v = ((vm >> t) & 1u) ? xc[offs[t]] : 0.f;
            sum += v * m[t];
        }
        out[outp + (size_t)c * 16384] = sum;
    }
}

extern "C" void kernel_launch(void* const* d_in, const int* in_sizes, int n_in,
                              void* d_out, int out_size, void* d_ws, size_t ws_size,
                              hipStream_t stream) {
    const float* x  = (const float*)d_in[0];
    const float* Wc = (const float*)d_in[1];
    const float* bc = (const float*)d_in[2];
    const float* We = (const float*)d_in[3];
    const float* be = (const float*)d_in[4];
    float* out = (float*)d_out;

    if (ws_size >= WS_NEED && d_ws != nullptr) {
        float* ws = (float*)d_ws;
        float* comp   = ws + COMP_F;
        float* wr     = ws + WR_F;
        float* logits = ws + LOG_F;
        hipLaunchKernelGGL(k0_wr,   dim3(289),  dim3(256), 0, stream, We, Wc, ws);
        hipLaunchKernelGGL(k1_comp, dim3(512),  dim3(256), 0, stream,
                           x, bc, /*wT=*/logits, comp);
        hipLaunchKernelGGL(k2_enc,  dim3(1280), dim3(256), 0, stream,
                           be, comp, wr, logits);
        hipLaunchKernelGGL(k2s_sm,  dim3(256),  dim3(256), 0, stream, logits);
        hipLaunchKernelGGL(k3_out,  dim3(1024), dim3(256), 0, stream,
                           x, logits, out);
    } else {
        hipLaunchKernelGGL(k_fused, dim3(256),  dim3(256), 0, stream,
                           x, Wc, bc, We, be, out);
    }
}